// Round 2
// baseline (279.421 us; speedup 1.0000x reference)
//
#include <hip/hip_runtime.h>

// y = W @ x + bias, W in COO (rows sorted), fp32.
// Wave-level segmented reduction: rows sorted => within a wave's 512
// contiguous nnz, every row except the wave's first/last row is fully
// contained -> plain store. Only boundary rows use atomicAdd.

constexpr int CHUNK = 8;  // nnz per thread; 2x float4/int4 vector loads

__global__ void init_y_bias(const float* __restrict__ bias,
                            float* __restrict__ y, int n) {
    int i = blockIdx.x * blockDim.x + threadIdx.x;
    if (i < n) y[i] = bias[i];
}

__global__ __launch_bounds__(256) void spmv_coo_segscan(
        const float* __restrict__ vals,
        const float* __restrict__ x,
        const int*   __restrict__ rows,
        const int*   __restrict__ cols,
        const float* __restrict__ bias,
        float*       __restrict__ y,
        long long nnz) {
    long long t  = (long long)blockIdx.x * blockDim.x + threadIdx.x;
    long long i0 = t * CHUNK;
    int lane = threadIdx.x & 63;

    // Is this whole wave's 512-nnz range in-bounds? (wave-uniform predicate)
    long long wave_start = (t - lane) * (long long)CHUNK;
    bool wave_full = (wave_start + 64LL * CHUNK) <= nnz;

    if (!wave_full) {
        // rare tail path: per-thread scalar with atomics (y pre-inited to bias)
        if (i0 >= nnz) return;
        float sum = 0.f;
        int cur = rows[i0];
        long long end = i0 + CHUNK < nnz ? i0 + CHUNK : nnz;
        for (long long k = i0; k < end; ++k) {
            int rk = rows[k];
            if (rk != cur) { atomicAdd(&y[cur], sum); sum = 0.f; cur = rk; }
            sum += vals[k] * x[cols[k]];
        }
        atomicAdd(&y[cur], sum);
        return;
    }

    // ---- full-wave path: all 64 lanes active, fully vectorized loads ----
    const float4* v4 = reinterpret_cast<const float4*>(vals + i0);
    const int4*   r4 = reinterpret_cast<const int4*>(rows + i0);
    const int4*   c4 = reinterpret_cast<const int4*>(cols + i0);
    float4 va = v4[0], vb = v4[1];
    int4   ra = r4[0], rb = r4[1];
    int4   ca = c4[0], cb = c4[1];

    float v[CHUNK] = {va.x, va.y, va.z, va.w, vb.x, vb.y, vb.z, vb.w};
    int   r[CHUNK] = {ra.x, ra.y, ra.z, ra.w, rb.x, rb.y, rb.z, rb.w};
    int   c[CHUNK] = {ca.x, ca.y, ca.z, ca.w, cb.x, cb.y, cb.z, cb.w};

    // issue all gathers up front (MLP)
    float g[CHUNK];
    #pragma unroll
    for (int k = 0; k < CHUNK; ++k) g[k] = x[c[k]];

    // ---- per-lane local segmented accumulation ----
    int   first_row = r[0];
    int   cur = first_row;
    float sum = v[0] * g[0];
    bool  head_done = false;
    int   head_row = 0;
    float head_sum = 0.f;
    #pragma unroll
    for (int k = 1; k < CHUNK; ++k) {
        if (r[k] != cur) {
            if (!head_done) { head_done = true; head_row = cur; head_sum = sum; }
            else {
                // segment started AND ended inside this lane => complete row
                y[cur] = bias[cur] + sum;
            }
            cur = r[k];
            sum = 0.f;
        }
        sum += v[k] * g[k];
    }
    int   tail_row = cur;
    float tail_sum = sum;

    // ---- inclusive segmented scan of tail sums across the wave ----
    // rows monotone: tail_row[j] == tail_row[i] (j<i) implies all lanes
    // between are single-segment with that row, so Hillis-Steele works.
    float scan = tail_sum;
    #pragma unroll
    for (int off = 1; off < 64; off <<= 1) {
        int   orow = __shfl_up(tail_row, off);
        float osum = __shfl_up(scan, off);
        if (lane >= off && orow == tail_row) scan += osum;
    }

    int   prev_tail_row  = __shfl_up(tail_row, 1);
    float prev_scan      = __shfl_up(scan, 1);
    int   next_first     = __shfl_down(first_row, 1);
    int   wave_first_row = __shfl(first_row, 0);
    int   wave_last_row  = __shfl(tail_row, 63);

    // ---- emit head segment (terminates a run from previous lanes) ----
    if (head_done) {
        float total = head_sum;
        if (lane > 0 && prev_tail_row == head_row) total += prev_scan;
        if (head_row == wave_first_row)
            atomicAdd(&y[head_row], total);      // may extend into prev wave
        else
            y[head_row] = bias[head_row] + total; // complete within this wave
    }

    // ---- emit tail run total at the last lane of each run ----
    bool tail_end = (lane == 63) || (next_first != tail_row);
    if (tail_end) {
        if (tail_row == wave_first_row || tail_row == wave_last_row)
            atomicAdd(&y[tail_row], scan);       // may span wave boundary
        else
            y[tail_row] = bias[tail_row] + scan; // complete within this wave
    }
}

extern "C" void kernel_launch(void* const* d_in, const int* in_sizes, int n_in,
                              void* d_out, int out_size, void* d_ws, size_t ws_size,
                              hipStream_t stream) {
    const float* vals = (const float*)d_in[0];
    const float* x    = (const float*)d_in[1];
    const float* bias = (const float*)d_in[2];
    const int*   rows = (const int*)d_in[3];
    const int*   cols = (const int*)d_in[4];
    float* y = (float*)d_out;

    const long long nnz = in_sizes[0];
    const int n_rows    = in_sizes[2];   // len(bias) == n_rows

    // 1) y = bias (needed for empty rows + rows receiving atomics)
    {
        int threads = 256;
        int blocks  = (n_rows + threads - 1) / threads;
        init_y_bias<<<blocks, threads, 0, stream>>>(bias, y, n_rows);
    }

    // 2) segmented COO reduce
    {
        long long n_thr = (nnz + CHUNK - 1) / CHUNK;
        int threads = 256;
        long long blocks = (n_thr + threads - 1) / threads;
        spmv_coo_segscan<<<(int)blocks, threads, 0, stream>>>(
            vals, x, rows, cols, bias, y, nnz);
    }
}

// Round 4
// 218.064 us; speedup vs baseline: 1.2814x; 1.2814x over previous
//
#include <hip/hip_runtime.h>

// y = W @ x + bias, W in COO (rows sorted), fp32.
// R4 (= R3 with compile fix): block-local LDS accumulation. Each block owns
// 4096 contiguous nnz (row range ~64 since avg 64 nnz/row). Per-thread run
// accumulation -> ds_add_f32 into acc[row-r0] -> coalesced epilogue stores.
// Only the two block-boundary rows use global atomics (~2 per block).

constexpr int       CHUNK = 16;                       // nnz per thread
constexpr int       BLOCK = 256;
constexpr long long SPAN  = (long long)BLOCK * CHUNK; // 4096 nnz per block
constexpr int       RMAX  = 6144;                     // LDS acc slots (24 KB)

// native vectors (HIP float4/int4 are classes -> rejected by nontemporal builtins)
typedef float vfloat4 __attribute__((ext_vector_type(4)));
typedef int   vint4   __attribute__((ext_vector_type(4)));

__global__ void init_y_bias(const float* __restrict__ bias,
                            float* __restrict__ y, int n) {
    int i = blockIdx.x * blockDim.x + threadIdx.x;
    if (i < n) y[i] = bias[i];
}

__device__ __forceinline__ void lds_add(float* p, float v) {
    // workgroup-scope relaxed fp add -> ds_add_f32 (no TCC involvement)
    __hip_atomic_fetch_add(p, v, __ATOMIC_RELAXED, __HIP_MEMORY_SCOPE_WORKGROUP);
}

__global__ __launch_bounds__(BLOCK) void spmv_coo_lds(
        const float* __restrict__ vals,
        const float* __restrict__ x,
        const int*   __restrict__ rows,
        const int*   __restrict__ cols,
        const float* __restrict__ bias,
        float*       __restrict__ y,
        long long nnz) {
    __shared__ float acc[RMAX];
    const int tid = threadIdx.x;
    const long long b0 = (long long)blockIdx.x * SPAN;
    if (b0 >= nnz) return;                       // whole block exits uniformly
    const long long bend = (b0 + SPAN < nnz) ? (b0 + SPAN) : nnz;

    // Block row range (uniform loads)
    const int r0    = rows[b0];
    const int rl    = rows[bend - 1];
    const int range = rl - r0 + 1;

    if (range <= RMAX) {
        for (int i = tid; i < range; i += BLOCK) acc[i] = 0.f;
        __syncthreads();

        const long long i0 = b0 + (long long)tid * CHUNK;
        if (i0 < bend) {
            if (i0 + CHUNK <= bend) {
                // ---- vectorized path: 16B-aligned (b0%4096==0, tid*16) ----
                const vfloat4* v4 = reinterpret_cast<const vfloat4*>(vals + i0);
                const vint4*   r4 = reinterpret_cast<const vint4*>(rows + i0);
                const vint4*   c4 = reinterpret_cast<const vint4*>(cols + i0);
                float v[CHUNK]; int r[CHUNK]; int c[CHUNK];
                #pragma unroll
                for (int q = 0; q < CHUNK / 4; ++q) {
                    vfloat4 vv = __builtin_nontemporal_load(v4 + q);
                    vint4   rr = __builtin_nontemporal_load(r4 + q);
                    vint4   cc = __builtin_nontemporal_load(c4 + q);
                    #pragma unroll
                    for (int j = 0; j < 4; ++j) {
                        v[4*q+j] = vv[j];
                        r[4*q+j] = rr[j];
                        c[4*q+j] = cc[j];
                    }
                }
                // issue all gathers up front (MLP); x stays L1/L2-cacheable
                float g[CHUNK];
                #pragma unroll
                for (int k = 0; k < CHUNK; ++k) g[k] = x[c[k]];

                int   cur = r[0];
                float sum = v[0] * g[0];
                #pragma unroll
                for (int k = 1; k < CHUNK; ++k) {
                    if (r[k] != cur) {           // row boundary: flush run
                        lds_add(&acc[cur - r0], sum);
                        cur = r[k];
                        sum = 0.f;
                    }
                    sum += v[k] * g[k];
                }
                lds_add(&acc[cur - r0], sum);
            } else {
                // ---- scalar tail ----
                int   cur = rows[i0];
                float sum = 0.f;
                long long kend = (i0 + CHUNK < bend) ? (i0 + CHUNK) : bend;
                for (long long k = i0; k < kend; ++k) {
                    int rk = rows[k];
                    if (rk != cur) { lds_add(&acc[cur - r0], sum); sum = 0.f; cur = rk; }
                    sum += vals[k] * x[cols[k]];
                }
                lds_add(&acc[cur - r0], sum);
            }
        }
        __syncthreads();

        // ---- coalesced epilogue: interior rows exclusively owned ----
        for (int i = tid; i < range; i += BLOCK) {
            int   r = r0 + i;
            float a = acc[i];
            if (r == r0 || r == rl) {
                if (a != 0.f) atomicAdd(&y[r], a);   // may span block boundary
            } else {
                y[r] = bias[r] + a;                  // plain coalesced store
            }
        }
    } else {
        // pathological row-gap fallback: per-thread global atomics
        const long long i0 = b0 + (long long)tid * CHUNK;
        if (i0 < bend) {
            int   cur = rows[i0];
            float sum = 0.f;
            long long kend = (i0 + CHUNK < bend) ? (i0 + CHUNK) : bend;
            for (long long k = i0; k < kend; ++k) {
                int rk = rows[k];
                if (rk != cur) { atomicAdd(&y[cur], sum); sum = 0.f; cur = rk; }
                sum += vals[k] * x[cols[k]];
            }
            atomicAdd(&y[cur], sum);
        }
    }
}

extern "C" void kernel_launch(void* const* d_in, const int* in_sizes, int n_in,
                              void* d_out, int out_size, void* d_ws, size_t ws_size,
                              hipStream_t stream) {
    const float* vals = (const float*)d_in[0];
    const float* x    = (const float*)d_in[1];
    const float* bias = (const float*)d_in[2];
    const int*   rows = (const int*)d_in[3];
    const int*   cols = (const int*)d_in[4];
    float* y = (float*)d_out;

    const long long nnz = in_sizes[0];
    const int n_rows    = in_sizes[2];   // len(bias) == n_rows

    // 1) y = bias (covers empty rows + rows receiving boundary atomics)
    {
        int threads = 256;
        int blocks  = (n_rows + threads - 1) / threads;
        init_y_bias<<<blocks, threads, 0, stream>>>(bias, y, n_rows);
    }

    // 2) block-local LDS-accumulated COO reduce
    {
        long long blocks = (nnz + SPAN - 1) / SPAN;
        spmv_coo_lds<<<(int)blocks, BLOCK, 0, stream>>>(
            vals, x, rows, cols, bias, y, nnz);
    }
}

// Round 5
// 208.931 us; speedup vs baseline: 1.3374x; 1.0437x over previous
//
#include <hip/hip_runtime.h>

// y = W @ x + bias, W in COO (rows sorted), fp32.
// R5: R4 with occupancy fix. LDS accumulator shrunk 24KB -> 3KB (rows are
// ~Poisson(64)-dense, a 2048-nnz block spans ~32 rows), so LDS never caps
// occupancy (8 blocks/CU = 32 waves). Streaming loads issued before the
// prologue so HBM latency overlaps LDS zeroing.

constexpr int       CHUNK = 8;                        // nnz per thread
constexpr int       BLOCK = 256;
constexpr long long SPAN  = (long long)BLOCK * CHUNK; // 2048 nnz per block
constexpr int       RMAX  = 768;                      // LDS acc slots (3 KB)

typedef float vfloat4 __attribute__((ext_vector_type(4)));
typedef int   vint4   __attribute__((ext_vector_type(4)));

__global__ void init_y_bias(const float* __restrict__ bias,
                            float* __restrict__ y, int n) {
    int i = blockIdx.x * blockDim.x + threadIdx.x;
    if (i < n) y[i] = bias[i];
}

__device__ __forceinline__ void lds_add(float* p, float v) {
    // workgroup-scope relaxed fp add -> ds_add_f32 (no TCC involvement)
    __hip_atomic_fetch_add(p, v, __ATOMIC_RELAXED, __HIP_MEMORY_SCOPE_WORKGROUP);
}

__global__ __launch_bounds__(BLOCK) void spmv_coo_lds(
        const float* __restrict__ vals,
        const float* __restrict__ x,
        const int*   __restrict__ rows,
        const int*   __restrict__ cols,
        const float* __restrict__ bias,
        float*       __restrict__ y,
        long long nnz) {
    __shared__ float acc[RMAX];
    const int tid = threadIdx.x;
    const long long b0 = (long long)blockIdx.x * SPAN;
    if (b0 >= nnz) return;                       // whole block exits uniformly
    const long long bend = (b0 + SPAN < nnz) ? (b0 + SPAN) : nnz;
    const bool full = (b0 + SPAN) <= nnz;        // block-uniform

    // ---- issue streaming loads FIRST: latency overlaps the prologue ----
    float v[CHUNK]; int r[CHUNK]; int c[CHUNK];
    const long long i0 = b0 + (long long)tid * CHUNK;
    if (full) {
        const vfloat4* v4 = reinterpret_cast<const vfloat4*>(vals + i0);
        const vint4*   r4 = reinterpret_cast<const vint4*>(rows + i0);
        const vint4*   c4 = reinterpret_cast<const vint4*>(cols + i0);
        #pragma unroll
        for (int q = 0; q < CHUNK / 4; ++q) {
            vfloat4 vv = __builtin_nontemporal_load(v4 + q);
            vint4   rr = __builtin_nontemporal_load(r4 + q);
            vint4   cc = __builtin_nontemporal_load(c4 + q);
            #pragma unroll
            for (int j = 0; j < 4; ++j) {
                v[4*q+j] = vv[j];
                r[4*q+j] = rr[j];
                c[4*q+j] = cc[j];
            }
        }
    }

    // ---- prologue: fixed-size zero (independent of row-range loads) ----
    #pragma unroll
    for (int i = tid; i < RMAX; i += BLOCK) acc[i] = 0.f;
    const int r0    = rows[b0];
    const int rl    = rows[bend - 1];
    const int range = rl - r0 + 1;
    __syncthreads();

    if (range <= RMAX) {
        if (full) {
            // gathers up front (MLP); x stays L1/L2-cacheable
            float g[CHUNK];
            #pragma unroll
            for (int k = 0; k < CHUNK; ++k) g[k] = x[c[k]];

            int   cur = r[0];
            float sum = v[0] * g[0];
            #pragma unroll
            for (int k = 1; k < CHUNK; ++k) {
                if (r[k] != cur) {               // row boundary: flush run
                    lds_add(&acc[cur - r0], sum);
                    cur = r[k];
                    sum = 0.f;
                }
                sum += v[k] * g[k];
            }
            lds_add(&acc[cur - r0], sum);
        } else if (i0 < bend) {
            // scalar partial-block path
            int   cur = rows[i0];
            float sum = 0.f;
            long long kend = (i0 + CHUNK < bend) ? (i0 + CHUNK) : bend;
            for (long long k = i0; k < kend; ++k) {
                int rk = rows[k];
                if (rk != cur) { lds_add(&acc[cur - r0], sum); sum = 0.f; cur = rk; }
                sum += vals[k] * x[cols[k]];
            }
            lds_add(&acc[cur - r0], sum);
        }
        __syncthreads();

        // ---- coalesced epilogue: interior rows exclusively owned ----
        for (int i = tid; i < range; i += BLOCK) {
            int   rr = r0 + i;
            float a  = acc[i];
            if (rr == r0 || rr == rl) {
                if (a != 0.f) atomicAdd(&y[rr], a);  // may span block boundary
            } else {
                y[rr] = bias[rr] + a;                // plain coalesced store
            }
        }
    } else {
        // pathological row-gap fallback: per-thread global atomics
        if (i0 < bend) {
            if (full) {
                float g[CHUNK];
                #pragma unroll
                for (int k = 0; k < CHUNK; ++k) g[k] = x[c[k]];
                int   cur = r[0];
                float sum = v[0] * g[0];
                #pragma unroll
                for (int k = 1; k < CHUNK; ++k) {
                    if (r[k] != cur) { atomicAdd(&y[cur], sum); sum = 0.f; cur = r[k]; }
                    sum += v[k] * g[k];
                }
                atomicAdd(&y[cur], sum);
            } else {
                int   cur = rows[i0];
                float sum = 0.f;
                long long kend = (i0 + CHUNK < bend) ? (i0 + CHUNK) : bend;
                for (long long k = i0; k < kend; ++k) {
                    int rk = rows[k];
                    if (rk != cur) { atomicAdd(&y[cur], sum); sum = 0.f; cur = rk; }
                    sum += vals[k] * x[cols[k]];
                }
                atomicAdd(&y[cur], sum);
            }
        }
    }
}

extern "C" void kernel_launch(void* const* d_in, const int* in_sizes, int n_in,
                              void* d_out, int out_size, void* d_ws, size_t ws_size,
                              hipStream_t stream) {
    const float* vals = (const float*)d_in[0];
    const float* x    = (const float*)d_in[1];
    const float* bias = (const float*)d_in[2];
    const int*   rows = (const int*)d_in[3];
    const int*   cols = (const int*)d_in[4];
    float* y = (float*)d_out;

    const long long nnz = in_sizes[0];
    const int n_rows    = in_sizes[2];   // len(bias) == n_rows

    // 1) y = bias (covers empty gap-rows + rows receiving boundary atomics)
    {
        int threads = 256;
        int blocks  = (n_rows + threads - 1) / threads;
        init_y_bias<<<blocks, threads, 0, stream>>>(bias, y, n_rows);
    }

    // 2) block-local LDS-accumulated COO reduce
    {
        long long blocks = (nnz + SPAN - 1) / SPAN;
        spmv_coo_lds<<<(int)blocks, BLOCK, 0, stream>>>(
            vals, x, rows, cols, bias, y, nnz);
    }
}